// Round 2
// baseline (470.068 us; speedup 1.0000x reference)
//
#include <hip/hip_runtime.h>

// UnPooling: x[32,112,112,64] f32 -> out[32,224,224,64] f32,
// out[:, ::2, ::2, :] = x, rest zero.
//
// Single full-coverage kernel (no memset): each block owns one input row
// (b,h) and writes the output row-pair (2h, 2h+1) = 2 x 57344 B, reading
// the 28672 B input row once.
//
// Key points vs previous rounds:
//  - PLAIN stores (no nontemporal): the rocclr fill that demonstrably
//    sustains 6.4 TB/s on this buffer uses the normal cached-store path;
//    R0's nt stores only reached ~2.7 TB/s.
//  - Full-coverage contiguous writes: every wave store instruction covers
//    1024 B contiguous, so all HBM channels stay busy (R1's data-only
//    scatter hit a 512B-stride / half-channel pattern at ~2.1 TB/s).
//  - No divergence on the even row: ALL lanes load; the non-data lane
//    groups (tid bit4 = 1) compute the same addresses as their neighbor
//    data group (bit4 doesn't feed the input index), so the extra lanes
//    are same-line broadcasts, not extra HBM traffic. A cndmask selects
//    zero for them, keeping the store one contiguous wave-wide write.
//  - 14 loads issued first, then 14 independent odd-row zero stores to
//    hide load latency, then the 14 dependent even-row stores.
typedef float f4 __attribute__((ext_vector_type(4)));

__global__ __launch_bounds__(256) void unpool_full(
    const f4* __restrict__ x, f4* __restrict__ out) {
    const int tid = threadIdx.x;
    const int h   = blockIdx.x;  // input row [0,112)
    const int b   = blockIdx.y;  // batch     [0,32)

    const f4* __restrict__ xrow = x + (size_t)(b * 112 + h) * 1792;
    f4* __restrict__ orow_e = out + (size_t)(b * 224 + 2 * h) * 3584;
    f4* __restrict__ orow_o = orow_e + 3584;

    const int lane16  = tid & 15;            // f4-within-pixel (channel/4)
    const int grp     = tid >> 5;            // input pixel sub-offset
    const bool is_data = ((tid >> 4) & 1) == 0;  // even output pixel?

    // Issue all 14 independent loads first (coalesced; bit4-groups alias
    // onto the same 256B lines — broadcast, no extra fetch).
    f4 v[14];
#pragma unroll
    for (int k = 0; k < 14; ++k) {
        v[k] = xrow[(grp + 8 * k) * 16 + lane16];
    }

    const f4 z = (f4){0.f, 0.f, 0.f, 0.f};

    // Odd output row: pure zeros, independent of the loads — issues while
    // loads are in flight.
#pragma unroll
    for (int k = 0; k < 14; ++k) {
        orow_o[tid + 256 * k] = z;
    }

    // Even output row: select data/zero per lane group; each wave store is
    // 1 KiB contiguous.
#pragma unroll
    for (int k = 0; k < 14; ++k) {
        orow_e[tid + 256 * k] = is_data ? v[k] : z;
    }
}

extern "C" void kernel_launch(void* const* d_in, const int* in_sizes, int n_in,
                              void* d_out, int out_size, void* d_ws, size_t ws_size,
                              hipStream_t stream) {
    dim3 grid(112, 32);  // one block per input row (b,h)
    dim3 block(256);
    unpool_full<<<grid, block, 0, stream>>>((const f4*)d_in[0], (f4*)d_out);
}

// Round 3
// 431.612 us; speedup vs baseline: 1.0891x; 1.0891x over previous
//
#include <hip/hip_runtime.h>

// UnPooling: x[32,112,112,64] f32 -> out[32,224,224,64] f32,
// out[:, ::2, ::2, :] = x, rest zero.
//
// R1 (memset + scatter) was the best so far; its scatter ran at only
// 2.1 TB/s with a maximally-shallow shape (25088 blocks, one dependent
// 16B load->store per thread). This round keeps the proven-fast memset
// (rocclr fill path, 6.3 TB/s on this buffer) and rebuilds ONLY the
// scatter per the G11 memory-bound recipe: 896 blocks x 256 threads,
// grid-stride over input rows, 28 independent load+store pairs per
// thread so load latency hides under deep unrolled work.
//
// Address identity: input row r = b*112+h -> output row 2r (since
// b*224+2h = 2r), so no integer division anywhere.
// Input f4 j = 16w + c4 -> even-row output f4 o = 32w + c4
//   = ((j & ~15) << 1) | (j & 15).
// Loads: 1 KiB contiguous per wave. Stores: 256B chunks @ 512B stride
// (inherent to data-only writes) — if this round doesn't reach copy-like
// BW, that pattern is confirmed as the limiter (H2 -> LDS repack next).
typedef float f4 __attribute__((ext_vector_type(4)));

__global__ __launch_bounds__(256) void unpool_scatter_deep(
    const f4* __restrict__ x, f4* __restrict__ out) {
    const int tid = threadIdx.x;

    // 3584 input rows total = 896 blocks x 4 rows each.
#pragma unroll 4
    for (int r = blockIdx.x; r < 3584; r += 896) {
        const f4* __restrict__ xrow = x + (size_t)r * 1792;
        f4* __restrict__ orow = out + (size_t)(2 * r) * 3584;

        // 1792 f4 per row = 7 chunks of 256.
#pragma unroll
        for (int k = 0; k < 7; ++k) {
            const int j = k * 256 + tid;
            const f4 v = xrow[j];
            const int o = ((j & ~15) << 1) | (j & 15);
            orow[o] = v;
        }
    }
}

extern "C" void kernel_launch(void* const* d_in, const int* in_sizes, int n_in,
                              void* d_out, int out_size, void* d_ws, size_t ws_size,
                              hipStream_t stream) {
    // Zeros (3/4 of output) on the proven 6.3 TB/s fill path.
    hipMemsetAsync(d_out, 0, (size_t)out_size, stream);

    dim3 grid(896);
    dim3 block(256);
    unpool_scatter_deep<<<grid, block, 0, stream>>>((const f4*)d_in[0], (f4*)d_out);
}